// Round 6
// baseline (467.303 us; speedup 1.0000x reference)
//
#include <hip/hip_runtime.h>

typedef short s8v  __attribute__((ext_vector_type(8)));
typedef float f4v  __attribute__((ext_vector_type(4)));
typedef int   v4i  __attribute__((ext_vector_type(4)));
typedef float v4f  __attribute__((ext_vector_type(4)));
typedef int   v2i  __attribute__((ext_vector_type(2)));

#define NNODES 8192
#define FDIM   256
#define NJC    2          // j-chunks; grid 256 = 1 block/CU
#define JLEN   4096       // columns-j per chunk
#define TROWS  64         // rows per block
#define KSTEP  32         // k per step = one PB k-tile
#define NSTEP  128        // JLEN / KSTEP
#define PHLEN  4          // steps per phase (R15: barrier every 4 steps)
#define PHASES 32         // NSTEP / PHLEN

__device__ __forceinline__ unsigned short f2bf(float f) {
    unsigned int x = __builtin_bit_cast(unsigned int, f);
    x += 0x7fffu + ((x >> 16) & 1u);
    return (unsigned short)(x >> 16);
}
// RTNE pack of 2 f32 -> 1 dword of 2 bf16
__device__ __forceinline__ int cvt_pk(float lo, float hi) {
    int r;
    asm("v_cvt_pk_bf16_f32 %0, %1, %2" : "=v"(r) : "v"(lo), "v"(hi));
    return r;
}

// Barrier WITHOUT vmcnt drain: LDS visibility needs only lgkmcnt(0);
// vmem data-deps are compiler-waited per-wave. Keeps prefetch in flight.
__device__ __forceinline__ void barrier_lds_only() {
    asm volatile("s_waitcnt lgkmcnt(0)" ::: "memory");
    __builtin_amdgcn_s_barrier();
    asm volatile("" ::: "memory");
}

// ---------------- Kernel 0: fused WT + wv ----------------
__global__ __launch_bounds__(256) void prep_kernel(const float* __restrict__ W,
                                                   const float* __restrict__ a,
                                                   unsigned short* __restrict__ WT,
                                                   float* __restrict__ v1,
                                                   float* __restrict__ v2) {
    if (blockIdx.x < 256) {
        int idx = blockIdx.x * 256 + threadIdx.x;
        int r = idx >> 8, c = idx & 255;
        WT[c * 256 + r] = f2bf(W[r * 256 + c]);
    } else {
        __shared__ float r1[256], r2[256];
        int b = blockIdx.x - 256, n = threadIdx.x;
        float w = W[(size_t)b * FDIM + n];
        r1[n] = w * a[n];
        r2[n] = w * a[FDIM + n];
        __syncthreads();
        for (int off = 128; off > 0; off >>= 1) {
            if (n < off) { r1[n] += r1[n + off]; r2[n] += r2[n + off]; }
            __syncthreads();
        }
        if (n == 0) { v1[b] = r1[0]; v2[b] = r2[0]; }
    }
}

// ---------------- Kernel 1: PB = tiled bf16 Wh; s1/s2 = h@v (fp32) ----------------
__global__ __launch_bounds__(128) void wh_kernel(
    const float* __restrict__ h, const unsigned short* __restrict__ WT,
    const float* __restrict__ v1, const float* __restrict__ v2,
    unsigned short* __restrict__ PB,
    float* __restrict__ s1, float* __restrict__ s2)
{
    __shared__ float v1_lds[FDIM], v2_lds[FDIM];
    int tid = threadIdx.x;
    v1_lds[tid] = v1[tid];       v1_lds[tid + 128] = v1[tid + 128];
    v2_lds[tid] = v2[tid];       v2_lds[tid + 128] = v2[tid + 128];
    __syncthreads();

    int w = tid >> 6, lane = tid & 63, q = lane >> 4, l15 = lane & 15;
    int i_base = blockIdx.x * 32 + w * 16;

    f4v acc[16] = {};
    float s1p = 0.f, s2p = 0.f;

    for (int k0 = 0; k0 < 256; k0 += 32) {
        const float* hp = h + (size_t)(i_base + l15) * FDIM + k0 + q * 8;
        f4v h0 = *(const f4v*)hp;
        f4v h1 = *(const f4v*)(hp + 4);
        union { v4i u; s8v s; } af;
        af.u[0] = cvt_pk(h0[0], h0[1]);
        af.u[1] = cvt_pk(h0[2], h0[3]);
        af.u[2] = cvt_pk(h1[0], h1[1]);
        af.u[3] = cvt_pk(h1[2], h1[3]);
#pragma unroll
        for (int j = 0; j < 4; ++j) {
            s1p += h0[j] * v1_lds[k0 + q * 8 + j] + h1[j] * v1_lds[k0 + q * 8 + 4 + j];
            s2p += h0[j] * v2_lds[k0 + q * 8 + j] + h1[j] * v2_lds[k0 + q * 8 + 4 + j];
        }
#pragma unroll
        for (int t = 0; t < 16; ++t) {
            s8v bf = *(const s8v*)(WT + (size_t)(t * 16 + l15) * FDIM + k0 + q * 8);
            acc[t] = __builtin_amdgcn_mfma_f32_16x16x32_bf16(af.s, bf, acc[t], 0, 0, 0);
        }
    }

    s1p += __shfl_xor(s1p, 16, 64);
    s1p += __shfl_xor(s1p, 32, 64);
    s2p += __shfl_xor(s2p, 16, 64);
    s2p += __shfl_xor(s2p, 32, 64);
    if (lane < 16) {
        s1[i_base + lane] = s1p;
        s2[i_base + lane] = s2p;
    }

#pragma unroll
    for (int t = 0; t < 16; ++t) {
        int i0 = i_base + q * 4;
        size_t a16 = (size_t)((i0 >> 5) * 16 + t) * 512
                   + l15 * 32 + ((i0 >> 3) & 3) * 8 + (i0 & 7);
        v2i pk;
        pk[0] = cvt_pk(acc[t][0], acc[t][1]);
        pk[1] = cvt_pk(acc[t][2], acc[t][3]);
        *(v2i*)(PB + a16) = pk;
    }
}

// ---------------- Kernel 2: producer-consumer, phased ring ----------------
// R15: P_lds = 8-slot ring (32 KB); ONE lgkm-only barrier per 4 steps
// (33 barriers vs 128). Producer (waves 4-7) computes phase p+1's slots
// from adj regs loaded a phase earlier (8-step ~2400cy slack vs ~900cy
// HBM latency) and issues phase p+2's loads up front. Consumer (waves
// 0-3) runs 4 uninterrupted steps of {bf-prefetch, 16 MFMA}. Reader
// slots (4p..4p+3) and writer slots (4p+4..4p+7) are disjoint mod 8,
// so one barrier per phase is race-free.
__global__ __launch_bounds__(512, 2) void attn_partial(
    const int* __restrict__ adj, const unsigned short* __restrict__ PB,
    const float* __restrict__ s1, const float* __restrict__ s2,
    float* __restrict__ Npart, float* __restrict__ dpart)
{
    __shared__ float s2_lds[JLEN];                      // 16 KB
    __shared__ unsigned short P_lds[8][TROWS * KSTEP];  // 8 x 4 KB ring
    __shared__ float dsum_lds[TROWS][4];                // 1 KB

    int tid = threadIdx.x;
    int jc = blockIdx.x & 1, rt = blockIdx.x >> 1;
    int j0 = jc * JLEN;

    // stage s2: 512 threads x 2 x 16B = 16 KB
    ((v4f*)s2_lds)[tid]       = ((const v4f*)(s2 + j0))[tid];
    ((v4f*)s2_lds)[tid + 512] = ((const v4f*)(s2 + j0))[tid + 512];

    bool producer = (tid >= 256);

    // producer decomposition: row m 0..63, k-slice idx 0..3, 8 j's/thread/step
    int p = tid & 255, m = p >> 2, idx = p & 3;
    int woff = ((idx * 64 + m) * 8) ^ (idx * 16);   // P_lds write addr
    float s1v = 0.f;
    const int* arow = adj + (size_t)(rt * TROWS + m) * NNODES + j0 + idx * 8;
    v4i A0[PHLEN] = {}, A1[PHLEN] = {}, B0[PHLEN] = {}, B1[PHLEN] = {};

    // consumer decomposition: wave g 0..3 -> cols g*64 + t*16 + l15
    int g = tid >> 6, lane = tid & 63, q = lane >> 4, l15 = lane & 15;
    const unsigned short* pbb = PB + (size_t)(jc * NSTEP) * 16 * 512 + l15 * 32 + q * 8;
    f4v acc[4][4] = {};
    s8v bfr[2][4];
    float dsum = 0.f;

// Producer phase body: compute P for steps 4*(PH+1)..+3 from AC regs
// (loaded one phase ago); issue adj loads for steps 4*(PH+2)..+3 into AN.
#define PPHASE(PH, AC0, AC1, AN0, AN1) do {                                   \
    _Pragma("unroll")                                                         \
    for (int u = 0; u < PHLEN; ++u) {                                         \
        int sl = 4 * ((PH) + 2) + u;                                          \
        int kn = (sl < NSTEP) ? sl * KSTEP : 0;                               \
        AN0[u] = __builtin_nontemporal_load((const v4i*)(arow + kn));         \
        AN1[u] = __builtin_nontemporal_load((const v4i*)(arow + kn + 4));     \
    }                                                                         \
    _Pragma("unroll")                                                         \
    for (int u = 0; u < PHLEN; ++u) {                                         \
        int sc = 4 * ((PH) + 1) + u;                                          \
        if (sc < NSTEP) {                                                     \
            v4f sA = *(const v4f*)&s2_lds[sc * KSTEP + idx * 8];              \
            v4f sB = *(const v4f*)&s2_lds[sc * KSTEP + idx * 8 + 4];          \
            float pa[4], pb_[4];                                              \
            _Pragma("unroll")                                                 \
            for (int j = 0; j < 4; ++j) {                                     \
                float x = s1v + sA[j];                                        \
                pa[j] = (AC0[u][j] > 0) ? __expf(fmaxf(x, 0.2f * x)) : 0.0f;  \
                dsum += pa[j];                                                \
                float x2 = s1v + sB[j];                                       \
                pb_[j] = (AC1[u][j] > 0) ? __expf(fmaxf(x2, 0.2f * x2)) : 0.0f;\
                dsum += pb_[j];                                               \
            }                                                                 \
            v4i pv;                                                           \
            pv[0] = cvt_pk(pa[0], pa[1]);   pv[1] = cvt_pk(pa[2], pa[3]);     \
            pv[2] = cvt_pk(pb_[0], pb_[1]); pv[3] = cvt_pk(pb_[2], pb_[3]);   \
            *(v4i*)&P_lds[sc & 7][woff] = pv;                                 \
        }                                                                     \
    }                                                                         \
} while (0)

// Consumer phase body: 4 steps of {issue bf(s+1), ds_read af, 16 MFMA}.
// bfr parity: step s uses bfr[u&1], loads bfr[(u+1)&1]; PHLEN even keeps
// bfr[0] as the first-step buffer of every phase.
#define CPHASE(PH) do {                                                       \
    _Pragma("unroll")                                                         \
    for (int u = 0; u < PHLEN; ++u) {                                         \
        int s = 4 * (PH) + u;                                                 \
        int sn = (s + 1 < NSTEP) ? s + 1 : 0;                                 \
        _Pragma("unroll")                                                     \
        for (int t = 0; t < 4; ++t)                                           \
            bfr[(u + 1) & 1][t] = *(const s8v*)(pbb + (size_t)(sn * 16 + g * 4 + t) * 512); \
        const unsigned short* pbuf = &P_lds[s & 7][0];                        \
        _Pragma("unroll")                                                     \
        for (int rh = 0; rh < 4; ++rh) {                                      \
            s8v af = *(const s8v*)&pbuf[((q * 64 + rh * 16 + l15) * 8) ^ (q * 16)]; \
            _Pragma("unroll")                                                 \
            for (int t = 0; t < 4; ++t)                                       \
                acc[rh][t] = __builtin_amdgcn_mfma_f32_16x16x32_bf16(af, bfr[u & 1][t], acc[rh][t], 0, 0, 0); \
        }                                                                     \
    }                                                                         \
} while (0)

    if (producer) {
        s1v = s1[rt * TROWS + m];
        // issue phase-(-1) source loads (steps 0..3) into A
#pragma unroll
        for (int u = 0; u < PHLEN; ++u) {
            A0[u] = __builtin_nontemporal_load((const v4i*)(arow + u * KSTEP));
            A1[u] = __builtin_nontemporal_load((const v4i*)(arow + u * KSTEP + 4));
        }
    } else {
        // preload step-0 B-frags
#pragma unroll
        for (int t = 0; t < 4; ++t)
            bfr[0][t] = *(const s8v*)(pbb + (size_t)(g * 4 + t) * 512);
    }
    barrier_lds_only();   // s2 staged

    // prologue phase -1: producer computes slots 0..3 from A, loads B (steps 4..7)
    if (producer) PPHASE(-1, A0, A1, B0, B1);
    barrier_lds_only();   // slots 0..3 visible

    for (int ph = 0; ph < PHASES; ph += 2) {
        if (producer) PPHASE(ph, B0, B1, A0, A1); else CPHASE(ph);
        barrier_lds_only();
        if (producer) PPHASE(ph + 1, A0, A1, B0, B1); else CPHASE(ph + 1);
        barrier_lds_only();
    }
#undef PPHASE
#undef CPHASE

    // partial denominator (producers hold dsum)
    if (producer) dsum_lds[m][idx] = dsum;
    __syncthreads();
    if (tid < TROWS) {
        float d = dsum_lds[tid][0] + dsum_lds[tid][1] + dsum_lds[tid][2] + dsum_lds[tid][3];
        dpart[jc * NNODES + rt * TROWS + tid] = d;
    }

    // partial numerator (consumers): row = rh*16 + q*4 + r, col = g*64 + t*16 + l15
    if (!producer) {
#pragma unroll
        for (int rh = 0; rh < 4; ++rh)
#pragma unroll
            for (int r = 0; r < 4; ++r) {
                int row = rh * 16 + q * 4 + r;
                float* base = Npart + ((size_t)(jc * NNODES) + rt * TROWS + row) * FDIM;
#pragma unroll
                for (int t = 0; t < 4; ++t)
                    __builtin_nontemporal_store(acc[rh][t][r], base + g * 64 + t * 16 + l15);
            }
    }
}

// ---------------- Kernel 3: reduce partials, normalize ----------------
__global__ __launch_bounds__(256) void reduce_kernel(
    const float* __restrict__ Npart, const float* __restrict__ dpart,
    float* __restrict__ out)
{
    int i = blockIdx.x, n = threadIdx.x;
    float d = 0.f, acc = 0.f;
#pragma unroll
    for (int jc = 0; jc < NJC; ++jc) {
        d += dpart[jc * NNODES + i];
        acc += Npart[((size_t)(jc * NNODES) + i) * FDIM + n];
    }
    out[(size_t)i * FDIM + n] = acc / fmaxf(d, 1e-30f);
}

extern "C" void kernel_launch(void* const* d_in, const int* in_sizes, int n_in,
                              void* d_out, int out_size, void* d_ws, size_t ws_size,
                              hipStream_t stream) {
    const float* h   = (const float*)d_in[0];
    const int*   adj = (const int*)d_in[1];
    const float* W   = (const float*)d_in[2];
    const float* a   = (const float*)d_in[3];
    float* out = (float*)d_out;

    char* ws = (char*)d_ws;
    unsigned short* PB = (unsigned short*)ws;                  // 4 MiB (tiled Wh)
    float* s1 = (float*)(ws + (4u << 20));                     // 32 KiB
    float* s2 = (float*)(ws + (4u << 20) + (32u << 10));       // 32 KiB
    unsigned short* WT = (unsigned short*)(ws + (4u << 20) + (64u << 10));   // 128 KiB
    float* v1 = (float*)(ws + (4u << 20) + (192u << 10));      // 1 KiB
    float* v2 = (float*)(ws + (4u << 20) + (193u << 10));      // 1 KiB
    float* dpart = (float*)(ws + (5u << 20));                  // 64 KiB
    float* Npart = (float*)(ws + (8u << 20));                  // 16 MiB

    hipLaunchKernelGGL(prep_kernel, dim3(512), dim3(256), 0, stream, W, a, WT, v1, v2);
    hipLaunchKernelGGL(wh_kernel, dim3(256), dim3(128), 0, stream, h, WT, v1, v2, PB, s1, s2);
    hipLaunchKernelGGL(attn_partial, dim3(128 * NJC), dim3(512), 0, stream,
                       adj, PB, s1, s2, Npart, dpart);
    hipLaunchKernelGGL(reduce_kernel, dim3(NNODES), dim3(256), 0, stream, Npart, dpart, out);
}